// Round 1
// baseline (2449.868 us; speedup 1.0000x reference)
//
#include <hip/hip_runtime.h>
#include <hip/hip_bf16.h>

#define BB 128
#define TT 256
#define VV 128
#define HH 1024
#define NG 4096   // 4*H gate columns (permuted: n = hc*4 + kg)
#define KK 1152   // V + H fused reduction dim

typedef unsigned short ushort_t;
typedef short bf16x8 __attribute__((ext_vector_type(8)));
typedef float f32x4 __attribute__((ext_vector_type(4)));

__device__ __forceinline__ ushort_t f2bf(float f) {
  unsigned u = __builtin_bit_cast(unsigned, f);
  u += 0x7fffu + ((u >> 16) & 1u);   // RTNE
  return (ushort_t)(u >> 16);
}

__device__ __forceinline__ uint4 pack8(const float* p) {
  uint4 r;
  r.x = (unsigned)f2bf(p[0]) | ((unsigned)f2bf(p[1]) << 16);
  r.y = (unsigned)f2bf(p[2]) | ((unsigned)f2bf(p[3]) << 16);
  r.z = (unsigned)f2bf(p[4]) | ((unsigned)f2bf(p[5]) << 16);
  r.w = (unsigned)f2bf(p[6]) | ((unsigned)f2bf(p[7]) << 16);
  return r;
}

__device__ __forceinline__ f32x4 MFMA(bf16x8 a, bf16x8 b, f32x4 c) {
  return __builtin_amdgcn_mfma_f32_16x16x32_bf16(a, b, c, 0, 0, 0);
}

// ---------------- init: h0/c0 copy, Wl->bf16, bias = bx+bh (permuted) -------
__global__ void init_misc(const float* __restrict__ h_in, const float* __restrict__ c_in,
                          const float* __restrict__ Wl, const float* __restrict__ bx,
                          const float* __restrict__ bh,
                          ushort_t* __restrict__ hbf0, float* __restrict__ cbuf,
                          ushort_t* __restrict__ wlbf, float* __restrict__ bias) {
  int i = blockIdx.x * blockDim.x + threadIdx.x;   // grid covers 131072 exactly
  hbf0[i] = f2bf(h_in[i]);
  cbuf[i] = c_in[i];
  wlbf[i] = f2bf(Wl[i]);
  if (i < NG) {
    int kg = i & 3, hc = i >> 2;
    bias[i] = bx[kg * HH + hc] + bh[kg * HH + hc];
  }
}

// ------------- build WcombT[n][k] bf16, n = hc*4+kg, k = [x(128) | h(1024)] --
__global__ void build_wcombT(const float* __restrict__ Wx, const float* __restrict__ Wh,
                             ushort_t* __restrict__ wcombT) {
  __shared__ float tile[32][33];
  const int k0 = blockIdx.x * 32, hc0 = blockIdx.y * 32, kg = blockIdx.z;
  const int tid = threadIdx.x;
#pragma unroll
  for (int p = 0; p < 4; ++p) {
    int kk = (tid >> 5) + p * 8, hh = tid & 31;
    int k = k0 + kk, hc = hc0 + hh;
    float v = (k < VV) ? Wx[kg * VV * HH + k * HH + hc]
                       : Wh[kg * HH * HH + (k - VV) * HH + hc];
    tile[kk][hh] = v;
  }
  __syncthreads();
#pragma unroll
  for (int p = 0; p < 4; ++p) {
    int hh = (tid >> 5) + p * 8, kk = tid & 31;
    int n = (hc0 + hh) * 4 + kg;
    wcombT[n * KK + k0 + kk] = f2bf(tile[kk][hh]);
  }
}

// ---------------- one LSTM timestep: gates GEMM + pointwise -----------------
// grid (4,64), 256 threads (4 waves: 2x2), WG tile 32(M b) x 64(N gate-cols)
__global__ __launch_bounds__(256) void lstm_step(
    const float* __restrict__ x, const ushort_t* __restrict__ wcombT,
    const float* __restrict__ bias, const ushort_t* __restrict__ hcur,
    ushort_t* __restrict__ hnext, float* __restrict__ cbuf,
    ushort_t* __restrict__ outs, int t,
    float* __restrict__ hout, float* __restrict__ cout) {
  __shared__ __align__(16) ushort_t As[2][32][72];   // [row b][k], +8 pad
  __shared__ __align__(16) ushort_t Bs[2][64][72];   // [col n][k] (B^T), +8 pad
  __shared__ float gs[32][65];

  const int tid = threadIdx.x;
  const int b0 = blockIdx.x * 32;
  const int n0 = blockIdx.y * 64;
  const int hc0 = blockIdx.y * 16;
  const int wave = tid >> 6, lane = tid & 63;
  const int wm = wave >> 1, wn = wave & 1;

  const int ar = tid >> 3, ak = (tid & 7) * 8;   // A staging: 32 rows x 64 k
  const int br = tid >> 2, bk = (tid & 3) * 16;  // B staging: 64 rows x 64 k

  f32x4 acc0 = {0.f, 0.f, 0.f, 0.f}, acc1 = {0.f, 0.f, 0.f, 0.f};

  // preload stage 0 (k0 = 0 -> x slice, fp32 -> bf16)
  uint4 av = pack8(x + (b0 + ar) * (TT * VV) + t * VV + ak);
  const ushort_t* pb0 = wcombT + (n0 + br) * KK + bk;
  uint4 bv0 = *(const uint4*)pb0;
  uint4 bv1 = *(const uint4*)(pb0 + 8);

  int buf = 0;
  for (int s = 0; s < 18; ++s) {
    *(uint4*)&As[buf][ar][ak] = av;
    *(uint4*)&Bs[buf][br][bk] = bv0;
    *(uint4*)&Bs[buf][br][bk + 8] = bv1;
    if (s < 17) {
      int k0 = (s + 1) * 64;
      if (k0 < VV) {
        av = pack8(x + (b0 + ar) * (TT * VV) + t * VV + k0 + ak);
      } else {
        av = *(const uint4*)(hcur + (b0 + ar) * HH + (k0 - VV) + ak);
      }
      const ushort_t* pb = wcombT + (n0 + br) * KK + k0 + bk;
      bv0 = *(const uint4*)pb;
      bv1 = *(const uint4*)(pb + 8);
    }
    __syncthreads();
#pragma unroll
    for (int kk = 0; kk < 64; kk += 32) {
      int koff = kk + (lane >> 4) * 8;
      bf16x8 af  = *(const bf16x8*)&As[buf][wm * 16 + (lane & 15)][koff];
      bf16x8 bf0 = *(const bf16x8*)&Bs[buf][wn * 32 + (lane & 15)][koff];
      bf16x8 bf1 = *(const bf16x8*)&Bs[buf][wn * 32 + 16 + (lane & 15)][koff];
      acc0 = MFMA(af, bf0, acc0);
      acc1 = MFMA(af, bf1, acc1);
    }
    buf ^= 1;
  }

  // scatter accumulators to LDS (C/D layout: col=lane&15, row=(lane>>4)*4+r)
#pragma unroll
  for (int j = 0; j < 2; ++j) {
    f32x4 a = j ? acc1 : acc0;
#pragma unroll
    for (int r = 0; r < 4; ++r) {
      int row = wm * 16 + (lane >> 4) * 4 + r;
      int col = wn * 32 + j * 16 + (lane & 15);
      gs[row][col] = a[r];
    }
  }
  __syncthreads();

  const bool last = (t == TT - 1);
#pragma unroll
  for (int it = 0; it < 2; ++it) {
    int idx = it * 256 + tid;
    int brow = idx >> 4, hq = idx & 15;
    int b = b0 + brow, hc = hc0 + hq;
    float gi = gs[brow][hq * 4 + 0] + bias[n0 + hq * 4 + 0];
    float gf = gs[brow][hq * 4 + 1] + bias[n0 + hq * 4 + 1];
    float gg = gs[brow][hq * 4 + 2] + bias[n0 + hq * 4 + 2];
    float go = gs[brow][hq * 4 + 3] + bias[n0 + hq * 4 + 3];
    float ig = 1.f / (1.f + expf(-gi));
    float fg = 1.f / (1.f + expf(-gf));
    float g  = tanhf(gg);
    float og = 1.f / (1.f + expf(-go));
    float cn = fg * cbuf[b * HH + hc] + ig * g;
    float hn = og * tanhf(cn);
    cbuf[b * HH + hc] = cn;
    hnext[b * HH + hc] = f2bf(hn);
    outs[(b * TT + t) * HH + hc] = f2bf(og);   // reference collects the o GATE
    if (last) {
      hout[b * HH + hc] = hn;
      cout[b * HH + hc] = cn;
    }
  }
}

// ---------------- logits = outs(bf16) @ Wl^T + bl ---------------------------
// grid 512, 256 threads (waves 2x2), WG tile 64(M) x 128(N=V)
__global__ __launch_bounds__(256) void logits_gemm(
    const ushort_t* __restrict__ outs, const ushort_t* __restrict__ wlbf,
    const float* __restrict__ bl, float* __restrict__ out) {
  __shared__ __align__(16) ushort_t As[2][64][72];
  __shared__ __align__(16) ushort_t Bs[2][128][72];
  const int tid = threadIdx.x;
  const int m0 = blockIdx.x * 64;
  const int wave = tid >> 6, lane = tid & 63;
  const int wm = wave >> 1, wn = wave & 1;
  const int ar = tid >> 2, ak = (tid & 3) * 16;   // 64 rows x 64 k
  const int br = tid >> 1, bk = (tid & 1) * 32;   // 128 rows x 64 k

  f32x4 acc[2][4];
#pragma unroll
  for (int i = 0; i < 2; ++i)
#pragma unroll
    for (int j = 0; j < 4; ++j) acc[i][j] = {0.f, 0.f, 0.f, 0.f};

  const ushort_t* pa = outs + (m0 + ar) * HH + ak;
  uint4 av0 = *(const uint4*)pa, av1 = *(const uint4*)(pa + 8);
  const ushort_t* pb = wlbf + br * HH + bk;
  uint4 bv0 = *(const uint4*)pb, bv1 = *(const uint4*)(pb + 8);
  uint4 bv2 = *(const uint4*)(pb + 16), bv3 = *(const uint4*)(pb + 24);

  int buf = 0;
  for (int s = 0; s < 16; ++s) {
    *(uint4*)&As[buf][ar][ak] = av0;
    *(uint4*)&As[buf][ar][ak + 8] = av1;
    *(uint4*)&Bs[buf][br][bk] = bv0;
    *(uint4*)&Bs[buf][br][bk + 8] = bv1;
    *(uint4*)&Bs[buf][br][bk + 16] = bv2;
    *(uint4*)&Bs[buf][br][bk + 24] = bv3;
    if (s < 15) {
      int k0 = (s + 1) * 64;
      const ushort_t* qa = outs + (m0 + ar) * HH + k0 + ak;
      av0 = *(const uint4*)qa; av1 = *(const uint4*)(qa + 8);
      const ushort_t* qb = wlbf + br * HH + k0 + bk;
      bv0 = *(const uint4*)qb; bv1 = *(const uint4*)(qb + 8);
      bv2 = *(const uint4*)(qb + 16); bv3 = *(const uint4*)(qb + 24);
    }
    __syncthreads();
#pragma unroll
    for (int kk = 0; kk < 64; kk += 32) {
      int koff = kk + (lane >> 4) * 8;
      bf16x8 a0 = *(const bf16x8*)&As[buf][wm * 32 + (lane & 15)][koff];
      bf16x8 a1 = *(const bf16x8*)&As[buf][wm * 32 + 16 + (lane & 15)][koff];
      bf16x8 b0 = *(const bf16x8*)&Bs[buf][wn * 64 + (lane & 15)][koff];
      bf16x8 b1 = *(const bf16x8*)&Bs[buf][wn * 64 + 16 + (lane & 15)][koff];
      bf16x8 b2 = *(const bf16x8*)&Bs[buf][wn * 64 + 32 + (lane & 15)][koff];
      bf16x8 b3 = *(const bf16x8*)&Bs[buf][wn * 64 + 48 + (lane & 15)][koff];
      acc[0][0] = MFMA(a0, b0, acc[0][0]);
      acc[0][1] = MFMA(a0, b1, acc[0][1]);
      acc[0][2] = MFMA(a0, b2, acc[0][2]);
      acc[0][3] = MFMA(a0, b3, acc[0][3]);
      acc[1][0] = MFMA(a1, b0, acc[1][0]);
      acc[1][1] = MFMA(a1, b1, acc[1][1]);
      acc[1][2] = MFMA(a1, b2, acc[1][2]);
      acc[1][3] = MFMA(a1, b3, acc[1][3]);
    }
    buf ^= 1;
  }
#pragma unroll
  for (int i = 0; i < 2; ++i)
#pragma unroll
    for (int j = 0; j < 4; ++j)
#pragma unroll
      for (int r = 0; r < 4; ++r) {
        int m = m0 + wm * 32 + i * 16 + (lane >> 4) * 4 + r;
        int v = wn * 64 + j * 16 + (lane & 15);
        out[m * VV + v] = acc[i][j][r] + bl[v];
      }
}

// ----------------------------------------------------------------------------
extern "C" void kernel_launch(void* const* d_in, const int* in_sizes, int n_in,
                              void* d_out, int out_size, void* d_ws, size_t ws_size,
                              hipStream_t stream) {
  const float* x    = (const float*)d_in[0];
  const float* h_in = (const float*)d_in[1];
  const float* c_in = (const float*)d_in[2];
  const float* Wx   = (const float*)d_in[3];
  const float* Wh   = (const float*)d_in[4];
  const float* bx   = (const float*)d_in[5];
  const float* bh   = (const float*)d_in[6];
  const float* Wl   = (const float*)d_in[7];
  const float* bl   = (const float*)d_in[8];

  char* ws = (char*)d_ws;
  size_t off = 0;
  ushort_t* wcombT = (ushort_t*)(ws + off); off += (size_t)NG * KK * 2;        // 9,437,184
  ushort_t* outs   = (ushort_t*)(ws + off); off += (size_t)BB * TT * HH * 2;   // 67,108,864
  ushort_t* hbf    = (ushort_t*)(ws + off); off += (size_t)2 * BB * HH * 2;    // ping-pong
  float*    cbuf   = (float*)(ws + off);    off += (size_t)BB * HH * 4;
  float*    bias   = (float*)(ws + off);    off += (size_t)NG * 4;
  ushort_t* wlbf   = (ushort_t*)(ws + off); off += (size_t)VV * HH * 2;

  float* out  = (float*)d_out;
  float* hout = out + (size_t)BB * TT * VV;        // 4,194,304
  float* cout = hout + (size_t)BB * HH;            // +131,072

  init_misc<<<dim3(512), dim3(256), 0, stream>>>(h_in, c_in, Wl, bx, bh,
                                                 hbf, cbuf, wlbf, bias);
  build_wcombT<<<dim3(36, 32, 4), dim3(256), 0, stream>>>(Wx, Wh, wcombT);

  for (int t = 0; t < TT; ++t) {
    ushort_t* hcur  = hbf + (size_t)(t & 1) * BB * HH;
    ushort_t* hnext = hbf + (size_t)((t + 1) & 1) * BB * HH;
    lstm_step<<<dim3(4, 64), dim3(256), 0, stream>>>(x, wcombT, bias, hcur, hnext,
                                                     cbuf, outs, t, hout, cout);
  }

  logits_gemm<<<dim3(512), dim3(256), 0, stream>>>(outs, wlbf, bl, out);
}